// Round 1
// 231.625 us; speedup vs baseline: 1.0149x; 1.0149x over previous
//
#include <hip/hip_runtime.h>

#define SIGMA_INV 1.0e4f          // 1/SIGMA
#define GAMMA_INV 1.0e4f          // 1/GAMMA
#define ZNEAR 1.0f
#define ZFAR 100.0f
#define EPSV 1e-10f

constexpr int KF = 8;
constexpr int NPIX = 4 * 512 * 512;
constexpr int NFACES = 200000;
// Dropped-slot relative weight <= e^LOG_CUT. Worst-case amplification:
// (prob_d/prob_max <= ~150) * (normalize amplification ~32x) ->
// e^-16 * 150 * 32 ~ 5e-4, well under the 3.9e-3 fp32-vs-ref baseline.
#define LOG_CUT (-16.0f)
// zinv window equivalent of LOG_CUT: zinv >= zmax - 16/1e4
#define ZWIN (16.0f / GAMMA_INV)

// ---------------------------------------------------------------------------
// Kernel 1: pack the 3 vertex normals of each face into ONE uint4 (16 B).
// 9 components x 14-bit fixed point (126 bits). Half-step err 6.1e-5; the
// final rgb/||rgb|| normalize amplifies ~32x -> ~2e-3, under threshold.
// Table = 3.2 MB -> L2-resident per XCD (R4 FETCH_SIZE confirmed). Plain
// (allocating) loads only: R7 proved nt loads bypass L2 -> 2x slower.
// ---------------------------------------------------------------------------
__global__ __launch_bounds__(256) void pack_face_normals14(
    const int*   __restrict__ faces,   // (F,3)
    const float* __restrict__ vnorm,   // (V,3)
    uint4*       __restrict__ fn,      // (F) packed
    int F)
{
    const int f = blockIdx.x * blockDim.x + threadIdx.x;
    if (f >= F) return;
    const int v[3] = { faces[f * 3 + 0], faces[f * 3 + 1], faces[f * 3 + 2] };

    unsigned long long lo = 0ull, hi = 0ull;
    int i = 0;
#pragma unroll
    for (int t = 0; t < 3; ++t) {
#pragma unroll
        for (int c = 0; c < 3; ++c, ++i) {
            const float x = vnorm[(size_t)v[t] * 3 + c];
            const unsigned long long code = (unsigned long long)(unsigned)
                __float2int_rn(fminf(fmaxf(x, -1.0f), 1.0f) * 8191.5f + 8191.5f);
            const int bp = 14 * i;
            if (bp < 64) {
                lo |= code << bp;
                if (bp > 50) hi |= code >> (64 - bp);
            } else {
                hi |= code << (bp - 64);
            }
        }
    }
    uint4 q;
    q.x = (unsigned)(lo & 0xFFFFFFFFull);
    q.y = (unsigned)(lo >> 32);
    q.z = (unsigned)(hi & 0xFFFFFFFFull);
    q.w = (unsigned)(hi >> 32);
    fn[f] = q;
}

__device__ __forceinline__ float dec14(const unsigned* w, int i) {
    const int bp = 14 * i;
    const int j = bp >> 5;
    const int off = bp & 31;
    unsigned long long u = (unsigned long long)w[j];
    if (j < 3) u |= (unsigned long long)w[j + 1] << 32;
    const unsigned code = (unsigned)(u >> off) & 0x3FFFu;
    return fmaf((float)code, 2.0f / 16383.0f, -1.0f);
}

// ---------------------------------------------------------------------------
// Kernel 2 (R8): survivor-bitmask restructure.
// Old shape: 8 unrolled masked gather bodies -> EVERY body runs per wave
// (P(any of 64 lanes survives at slot k) ~ 1.0) with ~12% lane utilization:
// 8 serialized L2 gathers + 8 decode/exp bodies for ~1 useful slot/lane.
// New shape: pass 1 reads ONLY p2f+zbuf (64 B/pix), builds a per-lane
// survivor bitmask; a while(rem) loop runs ~1.4x per wave, each iteration
// a FULL-WAVE gather of fn (16B) + bary (12B) + dists (4B) + one decode.
// Sigmoid moved into the survivor path (8 exps -> ~1 per pixel).
// Slot selection uses an unrolled cndmask chain: static register indexing
// only (runtime-indexed arrays would spill to scratch).
// ---------------------------------------------------------------------------
__global__ __launch_bounds__(256) void normal_shader_q14_bitmask(
    const int*   __restrict__ p2f,    // (N,H,W,K)
    const float* __restrict__ bary,   // (N,H,W,K,3)
    const float* __restrict__ zbuf,   // (N,H,W,K)
    const float* __restrict__ dists,  // (N,H,W,K)
    const uint4* __restrict__ fn,     // (F) packed face normals
    float*       __restrict__ out)    // (N,H,W,3)
{
    const int p = blockIdx.x * blockDim.x + threadIdx.x;
    if (p >= NPIX) return;

    // ---- coalesced vector loads: p2f + zbuf only (64 B/pixel) ----
    const int4* pf4 = reinterpret_cast<const int4*>(p2f + (size_t)p * KF);
    int4 fa = pf4[0], fb = pf4[1];
    int f[KF] = {fa.x, fa.y, fa.z, fa.w, fb.x, fb.y, fb.z, fb.w};

    const float4* z4 = reinterpret_cast<const float4*>(zbuf + (size_t)p * KF);
    float4 za = z4[0], zb = z4[1];
    float zv[KF] = {za.x, za.y, za.z, za.w, zb.x, zb.y, zb.z, zb.w};

    // ---- pass 1: z_inv + running max (no transcendentals, no bary) ----
    float zinv[KF];
    float zmax = EPSV;
#pragma unroll
    for (int k = 0; k < KF; ++k) {
        const float zi = (f[k] >= 0) ? (ZFAR - zv[k]) * (1.0f / (ZFAR - ZNEAR))
                                     : 0.0f;
        zinv[k] = zi;
        zmax = fmaxf(zmax, zi);
    }

    // ---- survivor bitmask: valid slot within ZWIN of the max ----
    const float zcut = zmax - ZWIN;
    unsigned rem = 0u;
#pragma unroll
    for (int k = 0; k < KF; ++k)
        if (f[k] >= 0 && zinv[k] > zcut) rem |= (1u << k);

    // ---- survivor loop: ~1 full-wave iteration (+~0.4 rare tie iters) ----
    float accx = 0.0f, accy = 0.0f, accz = 0.0f, wtot = 0.0f;
    while (rem) {
        // select lowest surviving slot via unrolled cndmask chain
        int ksel = 0, fsel = 0;
        float zsel = 0.0f;
#pragma unroll
        for (int k = KF - 1; k >= 0; --k) {
            if (rem & (1u << k)) { ksel = k; fsel = f[k]; zsel = zinv[k]; }
        }
        rem &= rem - 1u;   // clear that (lowest) bit

        // independent gathers: fn (16B), bary (12B), dists (4B)
        const size_t sidx = (size_t)p * KF + (size_t)ksel;
        const uint4 q = fn[fsel];
        const float* bp = bary + sidx * 3;
        const float b0 = bp[0];
        const float b1 = bp[1];
        const float b2 = bp[2];
        const float dvs = dists[sidx];

        unsigned w[4] = { q.x, q.y, q.z, q.w };
        const float nx = b0 * dec14(w, 0) + b1 * dec14(w, 3) + b2 * dec14(w, 6);
        const float ny = b0 * dec14(w, 1) + b1 * dec14(w, 4) + b2 * dec14(w, 7);
        const float nz = b0 * dec14(w, 2) + b1 * dec14(w, 5) + b2 * dec14(w, 8);

        const float prob = 1.0f / (1.0f + __expf(dvs * SIGMA_INV));
        const float wgt  = prob * __expf((zsel - zmax) * GAMMA_INV);
        wtot += wgt;
        accx = fmaf(wgt, nx, accx);
        accy = fmaf(wgt, ny, accy);
        accz = fmaf(wgt, nz, accz);
    }

    const float delta = fmaxf(__expf((EPSV - zmax) * GAMMA_INV), EPSV);
    const float inv_denom = 1.0f / (wtot + delta);
    const float r = (accx + delta) * inv_denom;   // bg = (1,1,1)
    const float g = (accy + delta) * inv_denom;
    const float b = (accz + delta) * inv_denom;

    const float nrm = sqrtf(r * r + g * g + b * b);
    const float invn = 1.0f / fmaxf(nrm, 1e-12f);

    float* o = out + (size_t)p * 3;
    o[0] = fmaf(r * invn, 0.5f, 0.5f);
    o[1] = fmaf(g * invn, 0.5f, 0.5f);
    o[2] = fmaf(b * invn, 0.5f, 0.5f);
}

// ---------------------------------------------------------------------------
// Fallback (R1 kernel) in case d_ws is too small for the 3.2 MB table.
// ---------------------------------------------------------------------------
__global__ __launch_bounds__(256) void normal_shader_direct(
    const int*   __restrict__ p2f,
    const float* __restrict__ bary,
    const float* __restrict__ zbuf,
    const float* __restrict__ dists,
    const float* __restrict__ vnorm,
    const int*   __restrict__ faces,
    float*       __restrict__ out)
{
    const int p = blockIdx.x * blockDim.x + threadIdx.x;
    if (p >= NPIX) return;

    const int4* pf4 = reinterpret_cast<const int4*>(p2f + (size_t)p * KF);
    int4 fa = pf4[0], fb = pf4[1];
    int f[KF] = {fa.x, fa.y, fa.z, fa.w, fb.x, fb.y, fb.z, fb.w};

    const float4* z4 = reinterpret_cast<const float4*>(zbuf + (size_t)p * KF);
    float4 za = z4[0], zb = z4[1];
    float zv[KF] = {za.x, za.y, za.z, za.w, zb.x, zb.y, zb.z, zb.w};

    const float4* d4 = reinterpret_cast<const float4*>(dists + (size_t)p * KF);
    float4 da = d4[0], db = d4[1];
    float dv[KF] = {da.x, da.y, da.z, da.w, db.x, db.y, db.z, db.w};

    const float4* b4 = reinterpret_cast<const float4*>(bary + (size_t)p * KF * 3);
    float bc[KF * 3];
#pragma unroll
    for (int i = 0; i < 6; ++i) {
        float4 t = b4[i];
        bc[4 * i + 0] = t.x; bc[4 * i + 1] = t.y;
        bc[4 * i + 2] = t.z; bc[4 * i + 3] = t.w;
    }

    float zinv[KF], prob[KF];
    float zmax = EPSV;
#pragma unroll
    for (int k = 0; k < KF; ++k) {
        const bool m = f[k] >= 0;
        const float zi = m ? (ZFAR - zv[k]) * (1.0f / (ZFAR - ZNEAR)) : 0.0f;
        const float pr = m ? 1.0f / (1.0f + __expf(dv[k] * SIGMA_INV)) : 0.0f;
        zinv[k] = zi;
        prob[k] = pr;
        zmax = fmaxf(zmax, zi);
    }

    float accx = 0.0f, accy = 0.0f, accz = 0.0f, wtot = 0.0f;
#pragma unroll
    for (int k = 0; k < KF; ++k) {
        const int idx = f[k] < 0 ? 0 : f[k];
        const int i3 = idx * 3;
        const int v0 = faces[i3 + 0];
        const int v1 = faces[i3 + 1];
        const int v2 = faces[i3 + 2];
        const float b0 = bc[k * 3 + 0];
        const float b1 = bc[k * 3 + 1];
        const float b2 = bc[k * 3 + 2];
        const float* n0 = vnorm + (size_t)v0 * 3;
        const float* n1 = vnorm + (size_t)v1 * 3;
        const float* n2 = vnorm + (size_t)v2 * 3;
        const float nx = b0 * n0[0] + b1 * n1[0] + b2 * n2[0];
        const float ny = b0 * n0[1] + b1 * n1[1] + b2 * n2[1];
        const float nz = b0 * n0[2] + b1 * n1[2] + b2 * n2[2];
        const float wgt = prob[k] * __expf((zinv[k] - zmax) * GAMMA_INV);
        wtot += wgt;
        accx = fmaf(wgt, nx, accx);
        accy = fmaf(wgt, ny, accy);
        accz = fmaf(wgt, nz, accz);
    }

    const float delta = fmaxf(__expf((EPSV - zmax) * GAMMA_INV), EPSV);
    const float inv_denom = 1.0f / (wtot + delta);
    const float r = (accx + delta) * inv_denom;
    const float g = (accy + delta) * inv_denom;
    const float b = (accz + delta) * inv_denom;

    const float nrm = sqrtf(r * r + g * g + b * b);
    const float invn = 1.0f / fmaxf(nrm, 1e-12f);

    float* o = out + (size_t)p * 3;
    o[0] = fmaf(r * invn, 0.5f, 0.5f);
    o[1] = fmaf(g * invn, 0.5f, 0.5f);
    o[2] = fmaf(b * invn, 0.5f, 0.5f);
}

extern "C" void kernel_launch(void* const* d_in, const int* in_sizes, int n_in,
                              void* d_out, int out_size, void* d_ws, size_t ws_size,
                              hipStream_t stream) {
    const int*   p2f   = (const int*)d_in[0];
    const float* bary  = (const float*)d_in[1];
    const float* zbuf  = (const float*)d_in[2];
    const float* dists = (const float*)d_in[3];
    const float* vnorm = (const float*)d_in[4];
    const int*   faces = (const int*)d_in[5];
    float* out = (float*)d_out;

    const int threads = 256;
    const size_t fn_bytes = (size_t)NFACES * sizeof(uint4);  // 3.2 MB

    if (ws_size >= fn_bytes) {
        uint4* fn = (uint4*)d_ws;
        pack_face_normals14<<<(NFACES + threads - 1) / threads, threads, 0, stream>>>(
            faces, vnorm, fn, NFACES);
        normal_shader_q14_bitmask<<<(NPIX + threads - 1) / threads, threads, 0, stream>>>(
            p2f, bary, zbuf, dists, fn, out);
    } else {
        normal_shader_direct<<<(NPIX + threads - 1) / threads, threads, 0, stream>>>(
            p2f, bary, zbuf, dists, vnorm, faces, out);
    }
}